// Round 1
// baseline (5846.981 us; speedup 1.0000x reference)
//
#include <hip/hip_runtime.h>
#include <hip/hip_fp16.h>
#include <math.h>

// Problem constants (fixed by reference setup_inputs)
#define RS 3072   // B*CH signals
#define NF 2048   // signal length N
#define MS 512    // measurements M

typedef _Float16 f16;
typedef _Float16 f16x8 __attribute__((ext_vector_type(8)));
typedef float f32x4 __attribute__((ext_vector_type(4)));

// idxs may be delivered as int64 (little-endian pairs [lo,0]) or int32.
// Sorted-unique indices => idxs[1] >= 1, so p[1]==0 iff int64 layout.
__device__ __forceinline__ int load_idx(const int* p, int j) {
    return (p[1] == 0) ? p[2 * j] : p[j];
}

#define PI_OVER_4096 7.669903939428206e-4f
#define CK0 0.022097086912079608f  // sqrt(1/2048)
#define CKN 0.03125f               // sqrt(2/2048) = 1/32 exactly

// Wg[j][k] = A[j,k] = c_k cos(pi*(2*idxs[j]+1)*k/4096)   (512 x 2048, k-contig)
// Wh[k][j] = A[j,k]                                       (2048 x 512, j-contig)
__global__ void build_w_kernel(const int* idxs, f16* Wg, f16* Wh) {
    int t = blockIdx.x * 256 + threadIdx.x;   // over MS*NF, exact grid
    int j = t >> 11, k = t & (NF - 1);
    int ii = load_idx(idxs, j);
    float ck = (k == 0) ? CK0 : CKN;
    int ph = ((2 * ii + 1) * k) & 8191;       // cos period = 8192 units of pi/4096
    float v = ck * cosf((float)ph * PI_OVER_4096);
    Wg[(size_t)j * NF + k] = (f16)v;
    Wh[(size_t)k * MS + j] = (f16)v;
}

// Dg[i][k] = D[k,i] = c_k cos(pi*(2i+1)k/4096)  (2048 x 2048, k-contig) for final idct
__global__ void build_d_kernel(f16* Dg) {
    int t = blockIdx.x * 256 + threadIdx.x;   // over NF*NF, exact grid
    int i = t >> 11, k = t & (NF - 1);
    float ck = (k == 0) ? CK0 : CKN;
    int ph = ((2 * i + 1) * k) & 8191;
    Dg[(size_t)i * NF + k] = (f16)(ck * cosf((float)ph * PI_OVER_4096));
}

// Bm[r][j] = 100 * x[r, idxs[j]]   (3072 x 512)
__global__ void build_b_kernel(const float* x, const int* idxs, f16* Bm) {
    int t = blockIdx.x * 256 + threadIdx.x;   // over RS*MS, exact grid
    int r = t >> 9, j = t & (MS - 1);
    int ii = load_idx(idxs, j);
    Bm[t] = (f16)(100.0f * x[(size_t)r * NF + ii]);
}

__device__ __forceinline__ void async_copy16(const void* g, void* l) {
    __builtin_amdgcn_global_load_lds(
        (__attribute__((address_space(1))) const void*)g,
        (__attribute__((address_space(3))) void*)l, 16, 0, 0);
}

// Generic fp16 GEMM, fp32 accumulate: acc[r][n] = sum_k A[r][k] * B[n][k]
// (B stored row-major [n][k], i.e. transposed-B / "B^T input" form, k-contiguous)
// MODE 0: T = acc                       (outH, stride ldo)
// MODE 1: Sh = soft(Sold - acc + Cc)    (ISTA step; outH==Sold==Sh, same-thread RMW)
// MODE 2: Cc = acc; Sh = soft(acc)      (first ISTA step from s0 = 0)
// MODE 3: outF = acc * 0.01             (final idct / SCALE)
template<int BM, int BN, int MODE>
__global__ __launch_bounds__(256) void gemm_k(
    const f16* __restrict__ A, const f16* __restrict__ B, int K, int lda,
    f16* outH, const f16* Sold, f16* Cc, float* outF, int ldo)
{
    constexpr int WM = BM / 2, WN = BN / 2;   // 4 waves in 2x2
    constexpr int IM = WM / 16, IN = WN / 16;
    __shared__ __align__(16) f16 As[BM * 32];
    __shared__ __align__(16) f16 Bs[BN * 32];

    const int tid = threadIdx.x;
    const int w = tid >> 6, l = tid & 63;
    const int wr = w >> 1, wc = w & 1;
    const int bm = blockIdx.y * BM, bn = blockIdx.x * BN;

    f32x4 acc[IM][IN];
#pragma unroll
    for (int a = 0; a < IM; ++a)
#pragma unroll
        for (int b = 0; b < IN; ++b)
            acc[a][b] = (f32x4){0.f, 0.f, 0.f, 0.f};

    const int lrow = l >> 2;        // 0..15: row within 16-row chunk per wave
    const int lk8 = (l & 3) * 8;    // 8-elem k offset within 32-elem row
    const int q = l >> 4, ln = l & 15;

    const f16* Abase = A + (size_t)bm * lda + lk8;
    const f16* Bbase = B + (size_t)bn * K + lk8;

    for (int k0 = 0; k0 < K; k0 += 32) {
        // ---- stage A tile [BM][32] : global_load_lds, 16B/lane, wave-contiguous LDS
#pragma unroll
        for (int i = 0; i < BM / 64; ++i) {
            int row = i * 64 + w * 16 + lrow;
            async_copy16(Abase + (size_t)row * lda + k0,
                         As + i * 2048 + w * 512 + l * 8);
        }
        // ---- stage B tile [BN][32]
#pragma unroll
        for (int i = 0; i < BN / 64; ++i) {
            int row = i * 64 + w * 16 + lrow;
            async_copy16(Bbase + (size_t)row * K + k0,
                         Bs + i * 2048 + w * 512 + l * 8);
        }
        __syncthreads();   // drains vmcnt (compiler emits full waitcnt before barrier)

        // ---- fragments: A[m=ln][k=q*8+j], B[n=ln][k=q*8+j]; both k-contig => ds_read_b128
        f16x8 af[IM], bf[IN];
#pragma unroll
        for (int im = 0; im < IM; ++im)
            af[im] = *(const f16x8*)(As + (wr * WM + im * 16 + ln) * 32 + q * 8);
#pragma unroll
        for (int in = 0; in < IN; ++in)
            bf[in] = *(const f16x8*)(Bs + (wc * WN + in * 16 + ln) * 32 + q * 8);
#pragma unroll
        for (int im = 0; im < IM; ++im)
#pragma unroll
            for (int in = 0; in < IN; ++in)
                acc[im][in] = __builtin_amdgcn_mfma_f32_16x16x32_f16(
                    af[im], bf[in], acc[im][in], 0, 0, 0);
        __syncthreads();
    }

    // ---- epilogue: C/D layout col = lane&15, row = (lane>>4)*4 + reg
#pragma unroll
    for (int im = 0; im < IM; ++im) {
#pragma unroll
        for (int in = 0; in < IN; ++in) {
#pragma unroll
            for (int r = 0; r < 4; ++r) {
                int gm = bm + wr * WM + im * 16 + q * 4 + r;
                int gn = bn + wc * WN + in * 16 + ln;
                size_t off = (size_t)gm * ldo + gn;
                float v = acc[im][in][r];
                if constexpr (MODE == 0) {
                    outH[off] = (f16)v;
                } else if constexpr (MODE == 1) {
                    float u = (float)Sold[off] - v + (float)Cc[off];
                    float a2 = fabsf(u) - 0.05f;
                    outH[off] = (f16)(a2 > 0.f ? copysignf(a2, u) : 0.f);
                } else if constexpr (MODE == 2) {
                    Cc[off] = (f16)v;
                    float a2 = fabsf(v) - 0.05f;
                    outH[off] = (f16)(a2 > 0.f ? copysignf(a2, v) : 0.f);
                } else {
                    outF[off] = v * 0.01f;
                }
            }
        }
    }
}

extern "C" void kernel_launch(void* const* d_in, const int* in_sizes, int n_in,
                              void* d_out, int out_size, void* d_ws, size_t ws_size,
                              hipStream_t stream) {
    const float* x = (const float*)d_in[0];
    const int* idxs = (const int*)d_in[1];

    // Workspace carve-up (~34 MB total). Dg (8 MB) aliases the front region
    // (Wg+Wh+Bm+Tm = 10 MB) — all four are dead before Dg is built.
    char* p = (char*)d_ws;
    auto take = [&](size_t n) { char* q = p; p += (n + 255) & ~(size_t)255; return q; };
    f16* Wg = (f16*)take((size_t)MS * NF * 2);  // 2 MB  A row-major
    f16* Wh = (f16*)take((size_t)NF * MS * 2);  // 2 MB  A^T row-major
    f16* Bm = (f16*)take((size_t)RS * MS * 2);  // 3 MB  measurements b
    f16* Tm = (f16*)take((size_t)RS * MS * 2);  // 3 MB  T = A s
    f16* Dg = (f16*)d_ws;                       // 8 MB  idct matrix (aliased)
    f16* Cc = (f16*)take((size_t)RS * NF * 2);  // 12.6 MB  c = A^T b
    f16* Sh = (f16*)take((size_t)RS * NF * 2);  // 12.6 MB  s state (fp16 master)

    build_w_kernel<<<dim3(MS * NF / 256), 256, 0, stream>>>(idxs, Wg, Wh);
    build_b_kernel<<<dim3(RS * MS / 256), 256, 0, stream>>>(x, idxs, Bm);

    // iteration 1 (s0 = 0):  c = Bm @ Wh ;  s1 = soft(c, 0.05)
    gemm_k<128, 128, 2><<<dim3(NF / 128, RS / 128), 256, 0, stream>>>(
        Bm, Wh, MS, MS, Sh, nullptr, Cc, nullptr, NF);

    // iterations 2..100:  T = s @ A^T (via Wg) ;  s = soft(s - T @ A + c, 0.05)
    for (int it = 0; it < 99; ++it) {
        gemm_k<64, 64, 0><<<dim3(MS / 64, RS / 64), 256, 0, stream>>>(
            Sh, Wg, NF, NF, Tm, nullptr, nullptr, nullptr, MS);
        gemm_k<128, 128, 1><<<dim3(NF / 128, RS / 128), 256, 0, stream>>>(
            Tm, Wh, MS, MS, Sh, Sh, Cc, nullptr, NF);
    }

    // output: idct(s) / 100 = (s @ Dg^T-form) * 0.01
    build_d_kernel<<<dim3(NF * NF / 256), 256, 0, stream>>>(Dg);
    gemm_k<128, 128, 3><<<dim3(NF / 128, RS / 128), 256, 0, stream>>>(
        Sh, Dg, NF, NF, nullptr, nullptr, nullptr, (float*)d_out, NF);
}

// Round 2
// 5471.255 us; speedup vs baseline: 1.0687x; 1.0687x over previous
//
#include <hip/hip_runtime.h>
#include <math.h>

// Problem constants (fixed by reference setup_inputs)
#define RS 3072   // B*CH signals
#define NF 2048   // signal length N
#define MS 512    // measurements M

typedef _Float16 f16;
typedef _Float16 f16x4 __attribute__((ext_vector_type(4)));
typedef _Float16 f16x8 __attribute__((ext_vector_type(8)));
typedef float f32x4 __attribute__((ext_vector_type(4)));

// idxs may be delivered as int64 (little-endian pairs [lo,0]) or int32.
// Sorted-unique indices => idxs[1] >= 1, so p[1]==0 iff int64 layout.
__device__ __forceinline__ int load_idx(const int* p, int j) {
    return (p[1] == 0) ? p[2 * j] : p[j];
}

#define PI_OVER_4096 7.669903939428206e-4f
#define CK0 0.022097086912079608f  // sqrt(1/2048)
#define CKN 0.03125f               // sqrt(2/2048)

// Wg[j][k] = A[j,k] = c_k cos(pi*(2*idxs[j]+1)*k/4096)   (512 x 2048, k-contig)
// Wh[k][j] = A[j,k]                                       (2048 x 512, j-contig)
__global__ void build_w_kernel(const int* idxs, f16* Wg, f16* Wh) {
    int t = blockIdx.x * 256 + threadIdx.x;   // over MS*NF
    int j = t >> 11, k = t & (NF - 1);
    int ii = load_idx(idxs, j);
    float ck = (k == 0) ? CK0 : CKN;
    int ph = ((2 * ii + 1) * k) & 8191;
    float v = ck * cosf((float)ph * PI_OVER_4096);
    Wg[(size_t)j * NF + k] = (f16)v;
    Wh[(size_t)k * MS + j] = (f16)v;
}

// Dg[i][k] = IDCT[i,k] = c_k cos(pi*(2i+1)k/4096)  (2048 x 2048, k-contig)
__global__ void build_d_kernel(f16* Dg) {
    int t = blockIdx.x * 256 + threadIdx.x;   // over NF*NF
    int i = t >> 11, k = t & (NF - 1);
    float ck = (k == 0) ? CK0 : CKN;
    int ph = ((2 * i + 1) * k) & 8191;
    Dg[(size_t)i * NF + k] = (f16)(ck * cosf((float)ph * PI_OVER_4096));
}

// Bm[r][j] = x[r, idxs[j]]  (UNSCALED; c = 100*acc in epilogue)
__global__ void build_b_kernel(const float* x, const int* idxs, f16* Bm) {
    int t = blockIdx.x * 256 + threadIdx.x;   // over RS*MS
    int r = t >> 9, j = t & (MS - 1);
    Bm[t] = (f16)(x[(size_t)r * NF + load_idx(idxs, j)]);
}

__global__ void msk_zero(float* m) { m[blockIdx.x * 256 + threadIdx.x] = 0.f; }
__global__ void msk_set(const int* idxs, float* m) {
    int j = blockIdx.x * 256 + threadIdx.x;
    if (j < MS) m[load_idx(idxs, j)] = 1.f;
}

__device__ __forceinline__ void async_copy16(const void* g, void* l) {
    __builtin_amdgcn_global_load_lds(
        (__attribute__((address_space(1))) const void*)g,
        (__attribute__((address_space(3))) void*)l, 16, 0, 0);
}

// H = clamp(20*(v+c), -1, 1) in f16 — MUST be the single shared definition so
// GEMM1's staged operand and GEMM2's epilogue subtraction round identically.
__device__ __forceinline__ f16 hclamp(f16 v, f16 c) {
    f16 s = (f16)((v + c) * (f16)20.0);
    s = s > (f16)1.0 ? (f16)1.0 : s;
    s = s < (f16)-1.0 ? (f16)-1.0 : s;
    return s;
}

// GEMM: acc[u][r] = sum_k A[u][k] * B[r][k]; A async-staged; B async (or
// virtual-H from v,c when MODE==1). Output-contiguous dim = u (MFMA M axis):
// per-thread acc regs map to 4 consecutive u => 8B/16B vector stores.
// Swizzle: blocks sharing a B(r)-strip share blockIdx%8 (same XCD) for L2 reuse.
// MODE 0: c = 100*acc; v = 0            (c-build, A=Wh, B=Bm)
// MODE 1: Y = acc                       (GEMM1, A=Wg, B=virtual H)
// MODE 2: v += 0.05*(acc - H(v,c))      (GEMM2, A=Wh, B=Y)
// MODE 3: MODE2 + overwrite v with F = v_new - 0.05*clamp(20(v_new+c))
// MODE 4: out = 0.01*acc + msk*x        (final idct, A=Dg, B=F)
template<int BU, int BR, int NP, int MODE>
__global__ __launch_bounds__(256) void gemm_k(
    const f16* __restrict__ A, const f16* __restrict__ B,
    const f16* vb, const f16* cb,
    f16* o16, f16* o16b,
    const float* __restrict__ xin, const float* __restrict__ msk,
    float* __restrict__ outF, int K, int ldo)
{
    constexpr int WU = BU / 2, WR = BR / 2;
    constexpr int IM = WU / 16, IN = WR / 16;
    __shared__ __align__(16) f16 As[BU * 32];
    __shared__ __align__(16) f16 Bs[BR * 32];

    const int tid = threadIdx.x;
    const int w = tid >> 6, l = tid & 63;
    const int wr = w >> 1, wc = w & 1;
    const int q = l >> 4, ln = l & 15;
    const int lrow = l >> 2, lk8 = (l & 3) * 8;

    // swizzled block decode: l = rgrp*(NP*8) + n*8 + (r%8)
    const int lbl = blockIdx.x;
    const int bu = ((lbl >> 3) & (NP - 1)) * BU;
    const int br = (((lbl >> 3) / NP) * 8 + (lbl & 7)) * BR;

    f32x4 acc[IM][IN];
#pragma unroll
    for (int a = 0; a < IM; ++a)
#pragma unroll
        for (int b = 0; b < IN; ++b)
            acc[a][b] = (f32x4){0.f, 0.f, 0.f, 0.f};

    const f16* Ab = A + (size_t)bu * K + lk8;
    const f16* Bb = (MODE == 1) ? (const f16*)nullptr : B + (size_t)br * K + lk8;

    for (int k0 = 0; k0 < K; k0 += 32) {
#pragma unroll
        for (int i = 0; i < BU / 64; ++i)
            async_copy16(Ab + (size_t)(i * 64 + w * 16 + lrow) * K + k0,
                         As + i * 2048 + w * 512 + l * 8);
        if constexpr (MODE == 1) {
            // virtual B: H = hclamp(v,c), BR==32 (32 rows x 32 k = 4 f16/thread)
            const int row = tid >> 3, k4 = (tid & 7) * 4;
            const size_t go = (size_t)(br + row) * NF + k0 + k4;
            f16x4 vg = *(const f16x4*)(vb + go);
            f16x4 cg = *(const f16x4*)(cb + go);
            f16x4 z;
#pragma unroll
            for (int e = 0; e < 4; ++e) z[e] = hclamp(vg[e], cg[e]);
            *(f16x4*)(Bs + row * 32 + k4) = z;
        } else {
#pragma unroll
            for (int i = 0; i < BR / 64; ++i)
                async_copy16(Bb + (size_t)(i * 64 + w * 16 + lrow) * K + k0,
                             Bs + i * 2048 + w * 512 + l * 8);
        }
        __syncthreads();

        f16x8 af[IM], bf[IN];
#pragma unroll
        for (int im = 0; im < IM; ++im)
            af[im] = *(const f16x8*)(As + (wr * WU + im * 16 + ln) * 32 + q * 8);
#pragma unroll
        for (int in = 0; in < IN; ++in)
            bf[in] = *(const f16x8*)(Bs + (wc * WR + in * 16 + ln) * 32 + q * 8);
#pragma unroll
        for (int im = 0; im < IM; ++im)
#pragma unroll
            for (int in = 0; in < IN; ++in)
                acc[im][in] = __builtin_amdgcn_mfma_f32_16x16x32_f16(
                    af[im], bf[in], acc[im][in], 0, 0, 0);
        __syncthreads();
    }

    // epilogue: C/D layout col(lane&15)=r-frag, row(q*4+reg)=u-frag (contig)
#pragma unroll
    for (int im = 0; im < IM; ++im) {
#pragma unroll
        for (int in = 0; in < IN; ++in) {
            const int u0 = bu + wr * WU + im * 16 + q * 4;
            const int r0 = br + wc * WR + in * 16 + ln;
            const size_t off = (size_t)r0 * ldo + u0;
            f32x4 a4 = acc[im][in];
            if constexpr (MODE == 0) {
                f16x4 cc, zz;
#pragma unroll
                for (int e = 0; e < 4; ++e) { cc[e] = (f16)(100.0f * a4[e]); zz[e] = (f16)0.0; }
                *(f16x4*)(o16 + off) = cc;     // c
                *(f16x4*)(o16b + off) = zz;    // v = 0
            } else if constexpr (MODE == 1) {
                f16x4 yy;
#pragma unroll
                for (int e = 0; e < 4; ++e) yy[e] = (f16)a4[e];
                *(f16x4*)(o16 + off) = yy;     // Y
            } else if constexpr (MODE == 2 || MODE == 3) {
                f16x4 v4 = *(const f16x4*)(vb + off);
                f16x4 c4 = *(const f16x4*)(cb + off);
                f16x4 st;
#pragma unroll
                for (int e = 0; e < 4; ++e) {
                    f16 hz = hclamp(v4[e], c4[e]);            // == GEMM1's operand
                    float vn = (float)v4[e] + 0.05f * (a4[e] - (float)hz);
                    if constexpr (MODE == 2) {
                        st[e] = (f16)vn;
                    } else {
                        float zf = fminf(fmaxf(20.0f * (vn + (float)c4[e]), -1.f), 1.f);
                        st[e] = (f16)(vn - 0.05f * zf);        // F = v99 - h100
                    }
                }
                *(f16x4*)(o16 + off) = st;     // v (or F, aliased into v buffer)
            } else {
                float4 xv = *(const float4*)(xin + off);
                float4 mk = *(const float4*)(msk + u0);
                float4 ov;
                ov.x = 0.01f * a4[0] + mk.x * xv.x;
                ov.y = 0.01f * a4[1] + mk.y * xv.y;
                ov.z = 0.01f * a4[2] + mk.z * xv.z;
                ov.w = 0.01f * a4[3] + mk.w * xv.w;
                *(float4*)(outF + off) = ov;
            }
        }
    }
}

extern "C" void kernel_launch(void* const* d_in, const int* in_sizes, int n_in,
                              void* d_out, int out_size, void* d_ws, size_t ws_size,
                              hipStream_t stream) {
    const float* x = (const float*)d_in[0];
    const int* idxs = (const int*)d_in[1];

    // Workspace (~32.2 MB total; known-safe vs. round-1's ~35 MB usage).
    // Dg (8 MB) aliases [Wg|Wh|BmY|c[0:1MB)] — all dead before build_d runs.
    char* p = (char*)d_ws;
    auto take = [&](size_t n) { char* q = p; p += (n + 255) & ~(size_t)255; return q; };
    f16* Wg  = (f16*)take((size_t)MS * NF * 2);   // 2 MB   A row-major (j,k)
    f16* Wh  = (f16*)take((size_t)NF * MS * 2);   // 2 MB   A^T row-major (n,j)
    f16* BmY = (f16*)take((size_t)RS * MS * 2);   // 3 MB   Bm, then Y (Bm dead after c-GEMM)
    f16* c16 = (f16*)take((size_t)RS * NF * 2);   // 12.6 MB  c (dead after loop)
    f16* v16 = (f16*)take((size_t)RS * NF * 2);   // 12.6 MB  v, then F
    float* msk = (float*)take((size_t)NF * 4);    // 8 KB   scatter mask
    f16* Dg  = (f16*)d_ws;                        // 8 MB   idct matrix (aliased)

    build_w_kernel<<<dim3(MS * NF / 256), 256, 0, stream>>>(idxs, Wg, Wh);
    build_b_kernel<<<dim3(RS * MS / 256), 256, 0, stream>>>(x, idxs, BmY);
    msk_zero<<<dim3(NF / 256), 256, 0, stream>>>(msk);
    msk_set<<<dim3(2), 256, 0, stream>>>(idxs, msk);

    // c = 100 * Bm @ A  (A=Wh u-dim n=2048/128 -> NP=16; r-panels 24; grid 384)
    gemm_k<128, 128, 16, 0><<<dim3(384), 256, 0, stream>>>(
        Wh, BmY, nullptr, nullptr, c16, v16, nullptr, nullptr, nullptr, MS, NF);

    // 99 iterations: Y = A*H (H virtual from v,c);  v += 0.05*(A^T Y - H)
    for (int it = 0; it < 99; ++it) {
        gemm_k<64, 32, 8, 1><<<dim3(768), 256, 0, stream>>>(
            Wg, nullptr, v16, c16, BmY, nullptr, nullptr, nullptr, nullptr, NF, MS);
        if (it < 98)
            gemm_k<64, 64, 32, 2><<<dim3(1536), 256, 0, stream>>>(
                Wh, BmY, v16, c16, v16, nullptr, nullptr, nullptr, nullptr, MS, NF);
        else
            gemm_k<64, 64, 32, 3><<<dim3(1536), 256, 0, stream>>>(
                Wh, BmY, v16, c16, v16, nullptr, nullptr, nullptr, nullptr, MS, NF);
    }

    // out = msk*x + 0.01 * F @ D   (F in v16 buffer; Dg overwrites Wg/Wh/BmY/c-head)
    build_d_kernel<<<dim3(NF * NF / 256), 256, 0, stream>>>(Dg);
    gemm_k<128, 128, 16, 4><<<dim3(384), 256, 0, stream>>>(
        Dg, v16, nullptr, nullptr, nullptr, nullptr, x, msk, (float*)d_out, NF, NF);
}